// Round 7
// baseline (446.356 us; speedup 1.0000x reference)
//
#include <hip/hip_runtime.h>
#include <hip/hip_bf16.h>
#include <stdint.h>

#define DEV static __device__ __forceinline__

typedef __attribute__((ext_vector_type(8))) short bf16x8;
typedef __attribute__((ext_vector_type(4))) float f32x4;
typedef unsigned int u32;

static constexpr int T = 4096;
static constexpr int BATCH = 8;
static constexpr int DM = 1024;            // d_model
static constexpr int M1 = BATCH * T;       // 32768 rows into GEMM1
static constexpr int M2 = BATCH * (T + 1); // 32776 rows into GEMM2
static constexpr int M2P = 129 * 256;      // 33024 padded rows for S
static constexpr int NCH = 64;
static constexpr int CL = T / NCH;
static constexpr int NT = 16;              // K tiles (BK=64, K=1024)

DEV unsigned short f2bf(float f) {
  union { float f; unsigned u; } v; v.f = f;
  unsigned u = v.u;
  return (unsigned short)((u + 0x7fffu + ((u >> 16) & 1u)) >> 16);
}
DEV float bf2f(unsigned short s) {
  union { unsigned u; float f; } v; v.u = ((unsigned)s) << 16;
  return v.f;
}
DEV bf16x8 pack8(float4 a, float4 b) {
  bf16x8 r;
  r[0] = (short)f2bf(a.x); r[1] = (short)f2bf(a.y);
  r[2] = (short)f2bf(a.z); r[3] = (short)f2bf(a.w);
  r[4] = (short)f2bf(b.x); r[5] = (short)f2bf(b.y);
  r[6] = (short)f2bf(b.z); r[7] = (short)f2bf(b.w);
  return r;
}

// ------------- transpose + convert weights: Wt[n][k] = W[k][n] -------------
__global__ void k_transpose(const float* __restrict__ w0, const float* __restrict__ w1,
                            unsigned short* __restrict__ t0, unsigned short* __restrict__ t1) {
  __shared__ float tile[32][33];
  const float* src = blockIdx.z ? w1 : w0;
  unsigned short* dst = blockIdx.z ? t1 : t0;
  int bx = blockIdx.x * 32;
  int by = blockIdx.y * 32;
  int tx = threadIdx.x & 31, ty = threadIdx.x >> 5;
#pragma unroll
  for (int r = 0; r < 32; r += 8)
    tile[ty + r][tx] = src[(by + ty + r) * DM + bx + tx];
  __syncthreads();
#pragma unroll
  for (int r = 0; r < 32; r += 8)
    dst[(bx + ty + r) * DM + by + tx] = f2bf(tile[tx][ty + r]);
}

// ---------------- bf16 MFMA GEMM: C = A @ Wt^T + bias ----------------
// Round-7 dataflow: B (weights) loaded L2->registers with PLAIN loads
// (compiler-managed counted vmcnt pipelining; B panel is L2-resident per
// XCD). Only A goes through LDS: reg-staged (fused fp32->bf16 convert for
// MODE 0), XOR slot^(row&7) swizzle (2-way = free), 2-deep dbuf, ONE raw
// s_barrier + lgkmcnt(0) per K-tile. 256x256 tile, BK=64, 8 waves (2Mx4N),
// wave = 128x64 out. Swapped-operand MFMA => contiguous per-lane stores.
// MODE 0: A = fp32, bf16 out. MODE 1: A = bf16, fp32 out, rows < Mvalid.
template <int MODE>
__global__ __launch_bounds__(512, 2) void k_gemm(const void* __restrict__ Asrc,
                                                 const unsigned short* __restrict__ Bt16,
                                                 const float* __restrict__ bias,
                                                 unsigned short* __restrict__ outb,
                                                 float* __restrict__ outf, int Mvalid) {
  __shared__ unsigned short lds[2 * 16384];  // 2 bufs x [256 rows][64 k] bf16 = 64 KiB

  const int tid = threadIdx.x;
  const int w = tid >> 6, l = tid & 63;
  const int wm = w >> 2, wn = w & 3;   // 2M x 4N wave grid
  const int lo = l & 15, hi = l >> 4;

  // bijective XCD swizzle (m204 general form)
  const int nwg = gridDim.x, orig = blockIdx.x;
  const int q8 = nwg >> 3, r8 = nwg & 7;
  const int xcd = orig & 7, idx = orig >> 3;
  const int wg = (xcd < r8 ? xcd * (q8 + 1) : r8 * (q8 + 1) + (xcd - r8) * q8) + idx;
  const int bm = wg >> 2, bn = wg & 3;
  const int blockM = bm * 256;
  const int blockN = bn * 256;

  const float* A32 = (const float*)Asrc;
  const unsigned short* A16 = (const unsigned short*)Asrc;

  f32x4 acc[8][4];
#pragma unroll
  for (int m = 0; m < 8; m++)
#pragma unroll
    for (int n = 0; n < 4; n++) acc[m][n] = (f32x4){0.f, 0.f, 0.f, 0.f};

  // ---- B fragment base: row (n) = blockN + wn*64 + nf*16 + lo; k elems = hi*8 + kh*32 + t*64
  const unsigned short* pB = Bt16 + (size_t)(blockN + wn * 64 + lo) * DM + hi * 8;

  // ---- A staging geometry: rnd 0..3 covers rows rnd*64 + (tid>>3); slot = tid&7
  const int sr = tid >> 3;           // row-in-round (0..63)
  const int ss = tid & 7;            // 16B slot (8 bf16)
  const int ssw = ss ^ (sr & 7);     // swizzled slot (rnd*64 doesn't change row&7)

  float4 sa[2][2];  // MODE 0 staging regs (half = 2 rnds)
  uint4 sb[2];      // MODE 1 staging regs

  auto loads_half = [&](int tt, int h) {
#pragma unroll
    for (int r2 = 0; r2 < 2; r2++) {
      const int rnd = h * 2 + r2;
      if (MODE == 0) {
        const float* p = A32 + (size_t)(blockM + rnd * 64 + sr) * DM + (size_t)tt * 64 + ss * 8;
        sa[r2][0] = *(const float4*)p;
        sa[r2][1] = *(const float4*)(p + 4);
      } else {
        const unsigned short* p = A16 + (size_t)(blockM + rnd * 64 + sr) * DM + (size_t)tt * 64 + ss * 8;
        sb[r2] = *(const uint4*)p;
      }
    }
  };
  auto write_half = [&](int buf, int h) {
#pragma unroll
    for (int r2 = 0; r2 < 2; r2++) {
      const int rnd = h * 2 + r2;
      unsigned short* d = lds + buf * 16384 + (rnd * 64 + sr) * 64 + ssw * 8;
      if (MODE == 0) *(bf16x8*)d = pack8(sa[r2][0], sa[r2][1]);
      else           *(uint4*)d = sb[r2];
    }
  };

  bf16x8 bq[2][4][2];

  // ---- prologue: B(0) issue, stage A(0) into buf 0
#pragma unroll
  for (int nf = 0; nf < 4; nf++)
#pragma unroll
    for (int kh = 0; kh < 2; kh++)
      bq[0][nf][kh] = *(const bf16x8*)(pB + (size_t)nf * 16 * DM + kh * 32);
  loads_half(0, 0);
  write_half(0, 0);
  loads_half(0, 1);
  write_half(0, 1);
  __builtin_amdgcn_sched_barrier(0);
  asm volatile("s_waitcnt lgkmcnt(0)");
  __builtin_amdgcn_sched_barrier(0);
  __builtin_amdgcn_s_barrier();
  __builtin_amdgcn_sched_barrier(0);

#define KHBLOCK(CB, KH)                                                       \
  _Pragma("unroll") for (int mf = 0; mf < 8; mf++) {                          \
    const int ml = wm * 128 + mf * 16 + lo;                                   \
    const bf16x8 aq = *(const bf16x8*)(lds + (CB) * 16384 + ml * 64 +         \
                                       ((((KH) << 2) | hi) ^ (ml & 7)) * 8);  \
    _Pragma("unroll") for (int nf = 0; nf < 4; nf++)                          \
      acc[mf][nf] = __builtin_amdgcn_mfma_f32_16x16x32_bf16(                  \
          bq[CB][nf][KH], aq, acc[mf][nf], 0, 0, 0);                          \
  }

#define TILE(tt, CB)                                                          \
  {                                                                           \
    const bool hasN = (tt) + 1 < NT;                                          \
    if (hasN) {                                                               \
      _Pragma("unroll") for (int nf = 0; nf < 4; nf++)                        \
        _Pragma("unroll") for (int kh = 0; kh < 2; kh++)                      \
          bq[(CB) ^ 1][nf][kh] = *(const bf16x8*)(pB + (size_t)nf * 16 * DM + \
                                                  ((tt) + 1) * 64 + kh * 32); \
      loads_half((tt) + 1, 0);                                                \
    }                                                                         \
    KHBLOCK(CB, 0)                                                            \
    if (hasN) { write_half((CB) ^ 1, 0); loads_half((tt) + 1, 1); }           \
    KHBLOCK(CB, 1)                                                            \
    if (hasN) write_half((CB) ^ 1, 1);                                        \
    __builtin_amdgcn_sched_barrier(0);                                        \
    asm volatile("s_waitcnt lgkmcnt(0)");                                     \
    __builtin_amdgcn_sched_barrier(0);                                        \
    __builtin_amdgcn_s_barrier();                                             \
    __builtin_amdgcn_sched_barrier(0);                                        \
  }

  for (int t = 0; t < NT; t += 2) {
    TILE(t, 0)
    TILE(t + 1, 1)
  }
#undef TILE
#undef KHBLOCK

  // ---- epilogue. Swapped mfma(B,A): lane l, reg j -> C[row][col] with
  // row = blockM + wm*128 + mf*16 + (l&15), col = blockN + wn*64 + nf*16 + (l>>4)*4 + j
#pragma unroll
  for (int mf = 0; mf < 8; mf++) {
    const int row = blockM + wm * 128 + mf * 16 + lo;
    if (MODE == 1 && row >= Mvalid) continue;
#pragma unroll
    for (int nf = 0; nf < 4; nf++) {
      const int col = blockN + wn * 64 + nf * 16 + hi * 4;
      const float4 bv = *(const float4*)(bias + col);
      if (MODE == 0) {
        ushort4 o;
        o.x = f2bf(acc[mf][nf][0] + bv.x);
        o.y = f2bf(acc[mf][nf][1] + bv.y);
        o.z = f2bf(acc[mf][nf][2] + bv.z);
        o.w = f2bf(acc[mf][nf][3] + bv.w);
        *(ushort4*)(outb + (size_t)row * DM + col) = o;
      } else {
        float4 o;
        o.x = acc[mf][nf][0] + bv.x;
        o.y = acc[mf][nf][1] + bv.y;
        o.z = acc[mf][nf][2] + bv.z;
        o.w = acc[mf][nf][3] + bv.w;
        *(float4*)(outf + (size_t)row * DM + col) = o;
      }
    }
  }
}

// ---------------- scan phase A: per-chunk local (zero-init) end state ----------------
__global__ void k_scan_partial(const unsigned short* __restrict__ proj,
                               const float* __restrict__ logit,
                               const float* __restrict__ z0,
                               float* __restrict__ chunkend) {
  int b = blockIdx.x >> 6, c = blockIdx.x & 63;
  int ch = threadIdx.x;
  float a = 1.f / (1.f + expf(-logit[ch >> 6]));
  int t0 = c * CL;
  const unsigned short* p = proj + (size_t)(b * T + t0) * DM + ch;
  float pprev = (t0 == 0) ? z0[ch] : bf2f(p[-DM]);
  float s = 0.f;
  for (int j = 0; j < CL; j++) {
    float pv = bf2f(p[(size_t)j * DM]);
    s = a * s + (1.f - a) * (pv - pprev);
    pprev = pv;
  }
  chunkend[(b * NCH + c) * DM + ch] = s;
}

// ---------------- scan phase B: serial cross-chunk combine ----------------
__global__ void k_scan_combine(const float* __restrict__ chunkend,
                               const float* __restrict__ logit,
                               const float* __restrict__ v0,
                               float* __restrict__ enter) {
  int b = blockIdx.x;
  int ch = threadIdx.x;
  float a = 1.f / (1.f + expf(-logit[ch >> 6]));
  float a2 = a * a, a4 = a2 * a2, a8 = a4 * a4, a16 = a8 * a8, a32 = a16 * a16;
  float aL = a32 * a32;  // a^64
  float e = v0[ch];
  enter[(b * NCH + 0) * DM + ch] = e;
  for (int c = 1; c < NCH; c++) {
    e = aL * e + chunkend[(b * NCH + c - 1) * DM + ch];
    enter[(b * NCH + c) * DM + ch] = e;
  }
}

// ---------------- scan phase C: final scan, write S (bf16) ----------------
__global__ void k_scan_final(const unsigned short* __restrict__ proj,
                             const float* __restrict__ logit,
                             const float* __restrict__ z0,
                             const float* __restrict__ v0,
                             const float* __restrict__ enter,
                             unsigned short* __restrict__ S) {
  int b = blockIdx.x >> 6, c = blockIdx.x & 63;
  int ch = threadIdx.x;
  float a = 1.f / (1.f + expf(-logit[ch >> 6]));
  int t0 = c * CL;
  const unsigned short* p = proj + (size_t)(b * T + t0) * DM + ch;
  unsigned short* so = S + (size_t)(b * (T + 1) + t0 + 1) * DM + ch;
  float pprev = (t0 == 0) ? z0[ch] : bf2f(p[-DM]);
  float s = enter[(b * NCH + c) * DM + ch];
  if (c == 0) S[(size_t)b * (T + 1) * DM + ch] = f2bf(v0[ch]);
  for (int j = 0; j < CL; j++) {
    float pv = bf2f(p[(size_t)j * DM]);
    s = a * s + (1.f - a) * (pv - pprev);
    pprev = pv;
    so[(size_t)j * DM] = f2bf(s);
  }
}

// zero the padded S rows [M2, M2P)
__global__ void k_pad(unsigned short* __restrict__ S) {
  int i = blockIdx.x * 256 + threadIdx.x;
  if (i < (M2P - M2) * DM) S[(size_t)M2 * DM + i] = 0;
}

extern "C" void kernel_launch(void* const* d_in, const int* in_sizes, int n_in,
                              void* d_out, int out_size, void* d_ws, size_t ws_size,
                              hipStream_t stream) {
  const float* inputs = (const float*)d_in[0];
  const float* z0     = (const float*)d_in[1];
  const float* W_in   = (const float*)d_in[2];
  const float* b_in   = (const float*)d_in[3];
  const float* W_out  = (const float*)d_in[4];
  const float* b_out  = (const float*)d_in[5];
  const float* slogit = (const float*)d_in[6];
  const float* v0     = (const float*)d_in[7];
  float* out = (float*)d_out;

  char* ws = (char*)d_ws;
  unsigned short* P16   = (unsigned short*)(ws);                 // 67,108,864 B
  unsigned short* S16   = (unsigned short*)(ws + 67108864);      // 67,633,152 B (33024 rows)
  unsigned short* WTin  = (unsigned short*)(ws + 134742016);     // 2,097,152 B
  unsigned short* WTout = (unsigned short*)(ws + 136839168);     // 2,097,152 B
  float* chunkend       = (float*)(ws + 138936320);              // 2,097,152 B
  float* enter          = (float*)(ws + 141033472);              // 2,097,152 B

  // 1. transpose+convert both weights
  k_transpose<<<dim3(32, 32, 2), 256, 0, stream>>>(W_in, W_out, WTin, WTout);
  // 2. GEMM1 (fused fp32->bf16 A-staging): proj = inputs @ W_in + b_in (bf16 out)
  k_gemm<0><<<dim3((M1 / 256) * 4), 512, 0, stream>>>(inputs, WTin, b_in, P16, nullptr, M1);
  // 3. scan: temporal diff + exponential smoothing
  k_scan_partial<<<dim3(BATCH * NCH), 1024, 0, stream>>>(P16, slogit, z0, chunkend);
  k_scan_combine<<<dim3(BATCH), 1024, 0, stream>>>(chunkend, slogit, v0, enter);
  k_scan_final<<<dim3(BATCH * NCH), 1024, 0, stream>>>(P16, slogit, z0, v0, enter, S16);
  k_pad<<<dim3(992), 256, 0, stream>>>(S16);
  // 4. GEMM2: out = S @ W_out + b_out (fp32 out, 32776 valid rows of 33024)
  k_gemm<1><<<dim3((M2P / 256) * 4), 512, 0, stream>>>(S16, WTout, b_out, nullptr, out, M2);
}

// Round 8
// 278.949 us; speedup vs baseline: 1.6001x; 1.6001x over previous
//
#include <hip/hip_runtime.h>
#include <hip/hip_bf16.h>
#include <stdint.h>

#define DEV static __device__ __forceinline__

typedef __attribute__((ext_vector_type(8))) short bf16x8;
typedef __attribute__((ext_vector_type(4))) float f32x4;
typedef unsigned int u32;

static constexpr int T = 4096;
static constexpr int BATCH = 8;
static constexpr int DM = 1024;            // d_model
static constexpr int M1 = BATCH * T;       // 32768 rows into GEMM1
static constexpr int M2 = BATCH * (T + 1); // 32776 rows into GEMM2
static constexpr int M2P = 257 * 128;      // 32896 padded rows for S (128-tile)
static constexpr int NCH = 64;
static constexpr int CL = T / NCH;
static constexpr int NT = 16;              // K tiles (BK=64, K=1024)

DEV unsigned short f2bf(float f) {
  union { float f; unsigned u; } v; v.f = f;
  unsigned u = v.u;
  return (unsigned short)((u + 0x7fffu + ((u >> 16) & 1u)) >> 16);
}
DEV float bf2f(unsigned short s) {
  union { unsigned u; float f; } v; v.u = ((unsigned)s) << 16;
  return v.f;
}

// async global->LDS, 16B per lane. lds dest wave-uniform; g per-lane.
DEV void gl_lds16(const unsigned short* g, unsigned short* lds) {
  __builtin_amdgcn_global_load_lds(
      (const __attribute__((address_space(1))) u32*)g,
      (__attribute__((address_space(3))) u32*)lds,
      16, 0, 0);
}

// ---------------- fp32 -> bf16 convert of inputs ----------------
__global__ void k_cvt_x(const float4* __restrict__ x, ushort4* __restrict__ o) {
  int i = blockIdx.x * 256 + threadIdx.x;
  float4 v = x[i];
  ushort4 r;
  r.x = f2bf(v.x); r.y = f2bf(v.y); r.z = f2bf(v.z); r.w = f2bf(v.w);
  o[i] = r;
}

// ------------- transpose + convert weights: Wt[n][k] = W[k][n] -------------
__global__ void k_transpose(const float* __restrict__ w0, const float* __restrict__ w1,
                            unsigned short* __restrict__ t0, unsigned short* __restrict__ t1) {
  __shared__ float tile[32][33];
  const float* src = blockIdx.z ? w1 : w0;
  unsigned short* dst = blockIdx.z ? t1 : t0;
  int bx = blockIdx.x * 32;
  int by = blockIdx.y * 32;
  int tx = threadIdx.x & 31, ty = threadIdx.x >> 5;
#pragma unroll
  for (int r = 0; r < 32; r += 8)
    tile[ty + r][tx] = src[(by + ty + r) * DM + bx + tx];
  __syncthreads();
#pragma unroll
  for (int r = 0; r < 32; r += 8)
    dst[(bx + ty + r) * DM + by + tx] = f2bf(tile[tx][ty + r]);
}

// ---------------- bf16 MFMA GEMM: C = A @ Wt^T + bias ----------------
// T3-minimum recipe (guide §5.5): 128x128 tile, BK=64, 4 waves (2x2),
// per-wave 64x64 (4x4 frags), double-buffered global_load_lds (2x32KB LDS),
// per K-step: STAGE(next, buf^1) -> ds_read 16 frags -> 32 MFMA -> ONE
// __syncthreads() (single vmcnt(0)+lgkmcnt(0)+barrier drain per tile).
// XOR swizzle slot^(row&7) via inverse-swizzled global source (rule 21).
// Swapped-operand MFMA (r7-verified): contiguous ushort4/float4 stores.
// MODE 0: bf16 out (proj). MODE 1: fp32 out, rows < Mvalid.
template <int MODE>
__global__ __launch_bounds__(256, 2) void k_gemm(const unsigned short* __restrict__ A16,
                                                 const unsigned short* __restrict__ Bt16,
                                                 const float* __restrict__ bias,
                                                 unsigned short* __restrict__ outb,
                                                 float* __restrict__ outf, int Mvalid) {
  __shared__ unsigned short lds[2][2][128 * 64];  // [buf][op A/B][row*64+k] = 64 KiB

  const int tid = threadIdx.x;
  const int w = tid >> 6, l = tid & 63;
  const int wm = w >> 1, wn = w & 1;   // 2x2 wave grid, per-wave 64x64
  const int lo = l & 15, hi = l >> 4;

  // bijective XCD swizzle (nwg % 8 == 0 for both grids)
  const int nwg = gridDim.x, orig = blockIdx.x;
  const int cpx = nwg >> 3;
  const int wg = (orig & 7) * cpx + (orig >> 3);
  const int bm = wg >> 3, bn = wg & 7;
  const int blockM = bm * 128;
  const int blockN = bn * 128;

  f32x4 acc[4][4];
#pragma unroll
  for (int m = 0; m < 4; m++)
#pragma unroll
    for (int n = 0; n < 4; n++) acc[m][n] = (f32x4){0.f, 0.f, 0.f, 0.f};

  // staging: wave w covers rows [w*32, w*32+32) as 4 chunks of 8 rows;
  // lane -> row +(l>>3), physical slot l&7. Global source inverse-swizzled
  // (slot (l&7)^((l>>3)&7); chunk base % 8 == 0 so row&7 == (l>>3)&7).
  const int ssw = (l & 7) ^ ((l >> 3) & 7);
  const unsigned short* pA[4];
  const unsigned short* pB[4];
#pragma unroll
  for (int c = 0; c < 4; c++) {
    const int rp = w * 32 + c * 8 + (l >> 3);
    pA[c] = A16 + (size_t)(blockM + rp) * DM + ssw * 8;
    pB[c] = Bt16 + (size_t)(blockN + rp) * DM + ssw * 8;
  }

  auto stage = [&](int tt, int buf) {
#pragma unroll
    for (int c = 0; c < 4; c++) {
      gl_lds16(pA[c] + (size_t)tt * 64, &lds[buf][0][(w * 32 + c * 8) * 64]);
      gl_lds16(pB[c] + (size_t)tt * 64, &lds[buf][1][(w * 32 + c * 8) * 64]);
    }
  };

  stage(0, 0);
  __syncthreads();

  for (int t = 0; t < NT; ++t) {
    const int cur = t & 1;
    if (t + 1 < NT) stage(t + 1, cur ^ 1);  // issue next-tile loads FIRST

    const unsigned short* La = lds[cur][0];
    const unsigned short* Lb = lds[cur][1];
    bf16x8 aq[4][2], bq[4][2];
#pragma unroll
    for (int kh = 0; kh < 2; kh++) {
      const int g = kh * 4 + hi;
#pragma unroll
      for (int mf = 0; mf < 4; mf++) {
        const int r = wm * 64 + mf * 16 + lo;
        aq[mf][kh] = *(const bf16x8*)(La + r * 64 + (g ^ (r & 7)) * 8);
      }
#pragma unroll
      for (int nf = 0; nf < 4; nf++) {
        const int r = wn * 64 + nf * 16 + lo;
        bq[nf][kh] = *(const bf16x8*)(Lb + r * 64 + (g ^ (r & 7)) * 8);
      }
    }
#pragma unroll
    for (int kh = 0; kh < 2; kh++)
#pragma unroll
      for (int mf = 0; mf < 4; mf++)
#pragma unroll
        for (int nf = 0; nf < 4; nf++)
          acc[mf][nf] = __builtin_amdgcn_mfma_f32_16x16x32_bf16(
              bq[nf][kh], aq[mf][kh], acc[mf][nf], 0, 0, 0);

    __syncthreads();  // single drain per K-tile (compiler emits vmcnt0+lgkm0)
  }

  // epilogue: swapped mfma(B,A) mapping (r7-verified):
  // row = blockM + wm*64 + mf*16 + (l&15); col = blockN + wn*64 + nf*16 + (l>>4)*4 + j
#pragma unroll
  for (int mf = 0; mf < 4; mf++) {
    const int row = blockM + wm * 64 + mf * 16 + lo;
    if (MODE == 1 && row >= Mvalid) continue;
#pragma unroll
    for (int nf = 0; nf < 4; nf++) {
      const int col = blockN + wn * 64 + nf * 16 + hi * 4;
      const float4 bv = *(const float4*)(bias + col);
      if (MODE == 0) {
        ushort4 o;
        o.x = f2bf(acc[mf][nf][0] + bv.x);
        o.y = f2bf(acc[mf][nf][1] + bv.y);
        o.z = f2bf(acc[mf][nf][2] + bv.z);
        o.w = f2bf(acc[mf][nf][3] + bv.w);
        *(ushort4*)(outb + (size_t)row * DM + col) = o;
      } else {
        float4 o;
        o.x = acc[mf][nf][0] + bv.x;
        o.y = acc[mf][nf][1] + bv.y;
        o.z = acc[mf][nf][2] + bv.z;
        o.w = acc[mf][nf][3] + bv.w;
        *(float4*)(outf + (size_t)row * DM + col) = o;
      }
    }
  }
}

// ---------------- scan phase A: per-chunk local (zero-init) end state ----------------
__global__ void k_scan_partial(const unsigned short* __restrict__ proj,
                               const float* __restrict__ logit,
                               const float* __restrict__ z0,
                               float* __restrict__ chunkend) {
  int b = blockIdx.x >> 6, c = blockIdx.x & 63;
  int ch = threadIdx.x;
  float a = 1.f / (1.f + expf(-logit[ch >> 6]));
  int t0 = c * CL;
  const unsigned short* p = proj + (size_t)(b * T + t0) * DM + ch;
  float pprev = (t0 == 0) ? z0[ch] : bf2f(p[-DM]);
  float s = 0.f;
  for (int j = 0; j < CL; j++) {
    float pv = bf2f(p[(size_t)j * DM]);
    s = a * s + (1.f - a) * (pv - pprev);
    pprev = pv;
  }
  chunkend[(b * NCH + c) * DM + ch] = s;
}

// ---------------- scan phase B: serial cross-chunk combine ----------------
__global__ void k_scan_combine(const float* __restrict__ chunkend,
                               const float* __restrict__ logit,
                               const float* __restrict__ v0,
                               float* __restrict__ enter) {
  int b = blockIdx.x;
  int ch = threadIdx.x;
  float a = 1.f / (1.f + expf(-logit[ch >> 6]));
  float a2 = a * a, a4 = a2 * a2, a8 = a4 * a4, a16 = a8 * a8, a32 = a16 * a16;
  float aL = a32 * a32;  // a^64
  float e = v0[ch];
  enter[(b * NCH + 0) * DM + ch] = e;
  for (int c = 1; c < NCH; c++) {
    e = aL * e + chunkend[(b * NCH + c - 1) * DM + ch];
    enter[(b * NCH + c) * DM + ch] = e;
  }
}

// ---------------- scan phase C: final scan, write S (bf16) ----------------
__global__ void k_scan_final(const unsigned short* __restrict__ proj,
                             const float* __restrict__ logit,
                             const float* __restrict__ z0,
                             const float* __restrict__ v0,
                             const float* __restrict__ enter,
                             unsigned short* __restrict__ S) {
  int b = blockIdx.x >> 6, c = blockIdx.x & 63;
  int ch = threadIdx.x;
  float a = 1.f / (1.f + expf(-logit[ch >> 6]));
  int t0 = c * CL;
  const unsigned short* p = proj + (size_t)(b * T + t0) * DM + ch;
  unsigned short* so = S + (size_t)(b * (T + 1) + t0 + 1) * DM + ch;
  float pprev = (t0 == 0) ? z0[ch] : bf2f(p[-DM]);
  float s = enter[(b * NCH + c) * DM + ch];
  if (c == 0) S[(size_t)b * (T + 1) * DM + ch] = f2bf(v0[ch]);
  for (int j = 0; j < CL; j++) {
    float pv = bf2f(p[(size_t)j * DM]);
    s = a * s + (1.f - a) * (pv - pprev);
    pprev = pv;
    so[(size_t)j * DM] = f2bf(s);
  }
}

// zero the padded S rows [M2, M2P)
__global__ void k_pad(unsigned short* __restrict__ S) {
  int i = blockIdx.x * 256 + threadIdx.x;  // 120*1024 elements
  S[(size_t)M2 * DM + i] = 0;
}

extern "C" void kernel_launch(void* const* d_in, const int* in_sizes, int n_in,
                              void* d_out, int out_size, void* d_ws, size_t ws_size,
                              hipStream_t stream) {
  const float* inputs = (const float*)d_in[0];
  const float* z0     = (const float*)d_in[1];
  const float* W_in   = (const float*)d_in[2];
  const float* b_in   = (const float*)d_in[3];
  const float* W_out  = (const float*)d_in[4];
  const float* b_out  = (const float*)d_in[5];
  const float* slogit = (const float*)d_in[6];
  const float* v0     = (const float*)d_in[7];
  float* out = (float*)d_out;

  char* ws = (char*)d_ws;
  unsigned short* X16   = (unsigned short*)(ws);                    // 67,108,864 B
  unsigned short* P16   = (unsigned short*)(ws + 67108864);         // 67,108,864 B
  unsigned short* S16   = (unsigned short*)(ws + 134217728);        // 67,371,008 B (32896 rows)
  unsigned short* WTin  = (unsigned short*)(ws + 201588736);        // 2,097,152 B
  unsigned short* WTout = (unsigned short*)(ws + 203685888);        // 2,097,152 B
  float* chunkend       = (float*)(ws + 205783040);                 // 2,097,152 B
  float* enter          = (float*)(ws + 207880192);                 // 2,097,152 B

  // 1. convert inputs to bf16
  k_cvt_x<<<32768, 256, 0, stream>>>((const float4*)inputs, (ushort4*)X16);
  // 2. transpose+convert both weights
  k_transpose<<<dim3(32, 32, 2), 256, 0, stream>>>(W_in, W_out, WTin, WTout);
  // 3. GEMM1: proj = inputs @ W_in + b_in (bf16 out), 256x8 = 2048 wgs
  k_gemm<0><<<dim3((M1 / 128) * 8), 256, 0, stream>>>(X16, WTin, b_in, P16, nullptr, M1);
  // 4. scan: temporal diff + exponential smoothing
  k_scan_partial<<<dim3(BATCH * NCH), 1024, 0, stream>>>(P16, slogit, z0, chunkend);
  k_scan_combine<<<dim3(BATCH), 1024, 0, stream>>>(chunkend, slogit, v0, enter);
  k_scan_final<<<dim3(BATCH * NCH), 1024, 0, stream>>>(P16, slogit, z0, v0, enter, S16);
  k_pad<<<dim3(480), 256, 0, stream>>>(S16);
  // 5. GEMM2: out = S @ W_out + b_out (fp32 out, 32776 valid rows of 32896), 257x8 = 2056 wgs
  k_gemm<1><<<dim3((M2P / 128) * 8), 256, 0, stream>>>(S16, WTout, b_out, nullptr, out, M2);
}